// Round 11
// baseline (58.350 us; speedup 1.0000x reference)
//
#include <hip/hip_runtime.h>
#include <hip/hip_bf16.h>
#include <cstddef>
#include <cstdint>

#define BS    8
#define M_PTS 1024
#define N_PTS 4096
#define C0    256
#define C1    128
#define C2    256
#define K1DIM 384   // C0 + C1

typedef __attribute__((ext_vector_type(8))) short bf16x8;
typedef __attribute__((ext_vector_type(4))) float f32x4;
typedef __attribute__((ext_vector_type(2))) float f32x2;

__device__ __forceinline__ ushort f2bf(float f) {
  union { float f; unsigned u; } v; v.f = f;
  unsigned r = v.u + 0x7fffu + ((v.u >> 16) & 1u);   // RNE
  return (ushort)(r >> 16);
}

// packed fp32; per-half rounding identical to v_mul/v_add (validated r7/r10)
__device__ __forceinline__ f32x2 pk_mul(f32x2 a, f32x2 b) {
  f32x2 r; asm("v_pk_mul_f32 %0, %1, %2" : "=v"(r) : "v"(a), "v"(b)); return r;
}
__device__ __forceinline__ f32x2 pk_add(f32x2 a, f32x2 b) {
  f32x2 r; asm("v_pk_add_f32 %0, %1, %2" : "=v"(r) : "v"(a), "v"(b)); return r;
}

// ---------------------------------------------------------------------------
// Merged prep: blocks [0,2048) transpose feats (BS,C0,M)->(BS,M,C0);
// blocks [2048,2432) convert W1/W2 to bf16 MFMA A-fragment order
// ---------------------------------------------------------------------------
__global__ __launch_bounds__(256) void prep_k(
    const float* __restrict__ feats, const float* __restrict__ W1,
    const float* __restrict__ W2, float* __restrict__ featsT,
    ushort* __restrict__ W1f, ushort* __restrict__ W2f) {
  __shared__ float tile[32][33];
  const int t = threadIdx.x;
  if (blockIdx.x < 2048) {
    const int bx = blockIdx.x & 31;          // M tile
    const int by = (blockIdx.x >> 5) & 7;    // C0 tile
    const int bz = blockIdx.x >> 8;          // batch
    const int tx = t & 31, ty = t >> 5;
    const float* ip = feats + (size_t)bz * C0 * M_PTS;
    float*       op = featsT + (size_t)bz * C0 * M_PTS;
    const int r0 = by * 32, c0 = bx * 32;
#pragma unroll
    for (int i = 0; i < 4; ++i)
      tile[ty + i * 8][tx] = ip[(size_t)(r0 + ty + i * 8) * M_PTS + c0 + tx];
    __syncthreads();
#pragma unroll
    for (int i = 0; i < 4; ++i)
      op[(size_t)(c0 + ty + i * 8) * C0 + r0 + tx] = tile[tx][ty + i * 8];
  } else {
    const int id = (blockIdx.x - 2048) * 256 + t;
    if (id < C2 * K1DIM) {
      int m = id / K1DIM, k = id - m * K1DIM;
      int off = (((m >> 4) * 12 + (k >> 5)) * 4 + ((k >> 3) & 3)) * 128 + (m & 15) * 8 + (k & 7);
      W1f[off] = f2bf(W1[id]);
    }
    if (id < C2 * C2) {
      int m = id >> 8, k = id & 255;
      int off = (((m >> 4) * 8 + (k >> 5)) * 4 + ((k >> 3) & 3)) * 128 + (m & 15) * 8 + (k & 7);
      W2f[off] = f2bf(W2[id]);
    }
  }
}

// ---------------------------------------------------------------------------
// Scan-only kernel at 100% occupancy: 2048 blocks x 256 thr (8 blocks/CU,
// 32 waves/CU), LDS = pts only (16 KB). 16 queries/block, 16 subs/query x 64
// points each. Exact r10 arithmetic: pair-packed SoA + v_pk distances +
// fmed3f/cndmask insertion + stable butterfly merge (4 stages).
// ---------------------------------------------------------------------------
__global__ __launch_bounds__(256, 8) void nn_scan_k(
    const float* __restrict__ xyz, const float* __restrict__ pxyz,
    int* __restrict__ idx3, float* __restrict__ w3) {
  __shared__ float4 pts4[1024];                   // 512 pairs x 32 B = 16 KB
  const int t  = threadIdx.x;
  const int b  = blockIdx.x & 7;                  // XCD-pinned batch
  const int n0 = (blockIdx.x >> 3) * 16;
  const int q  = t >> 4, sub = t & 15;

  // ---- stage 2 SoA-pairs per thread, XOR-staggered slot = p ^ ((p>>6)&7) ----
#pragma unroll
  for (int it = 0; it < 2; ++it) {
    const int p = t + it * 256;                   // pair index 0..511
    const float2* xb = (const float2*)(xyz + (size_t)b * 3 * M_PTS + 6 * p);
    const float2 A = xb[0], B = xb[1], C = xb[2];
    const float x0 = A.x, y0 = A.y, z0 = B.x, x1 = B.y, y1 = C.x, z1 = C.y;
    const float s0 = __fadd_rn(__fadd_rn(__fmul_rn(x0, x0), __fmul_rn(y0, y0)),
                               __fmul_rn(z0, z0));
    const float s1 = __fadd_rn(__fadd_rn(__fmul_rn(x1, x1), __fmul_rn(y1, y1)),
                               __fmul_rn(z1, z1));
    const int U = p ^ ((p >> 6) & 7);
    pts4[U * 2 + 0] = (float4){x0, x1, y0, y1};
    pts4[U * 2 + 1] = (float4){z0, z1, s0, s1};
  }

  const int gn = n0 + q;
  const float qx = pxyz[((size_t)b * N_PTS + gn) * 3 + 0];
  const float qy = pxyz[((size_t)b * N_PTS + gn) * 3 + 1];
  const float qz = pxyz[((size_t)b * N_PTS + gn) * 3 + 2];
  const float qq = __fadd_rn(__fadd_rn(__fmul_rn(qx, qx), __fmul_rn(qy, qy)),
                             __fmul_rn(qz, qz));
  __syncthreads();

  // ---- scan: 16 subs x 32 pairs; packed distances, exact select ----
  float d0 = 3.4e38f, d1 = 3.4e38f, d2 = 3.4e38f;
  int   i0 = 0, i1 = 0, i2 = 0;
  {
    const f32x2 Qx2 = {qx, qx}, Qy2 = {qy, qy}, Qz2 = {qz, qz};
    const f32x2 Qq2 = {qq, qq}, Mn2 = {-2.0f, -2.0f};
    const int stag = sub >> 1;
    int pe[8];
#pragma unroll
    for (int e = 0; e < 8; ++e) pe[e] = (sub * 32 + (e ^ stag)) * 2;  // de-swizzle
    for (int jb = 0; jb < 4; ++jb) {
#pragma unroll
      for (int e = 0; e < 8; ++e) {
        const float4 lo = pts4[pe[e] + jb * 16];
        const float4 hi = pts4[pe[e] + jb * 16 + 1];
        const f32x2 Xp = {lo.x, lo.y}, Yp = {lo.z, lo.w};
        const f32x2 Zp = {hi.x, hi.y}, Sp = {hi.z, hi.w};
        const f32x2 dotp = pk_add(pk_add(pk_mul(Qx2, Xp), pk_mul(Qy2, Yp)),
                                  pk_mul(Qz2, Zp));
        const f32x2 dp = pk_add(pk_add(Qq2, pk_mul(dotp, Mn2)), Sp);
        {
          const float d = dp.x; const int m = jb * 16 + 2 * e;
          const bool c0 = d < d0, c1 = d < d1, c2 = d < d2;
          i2 = c1 ? i1 : (c2 ? m : i2);
          i1 = c0 ? i0 : (c1 ? m : i1);
          i0 = c0 ? m : i0;
          d2 = __builtin_amdgcn_fmed3f(d, d1, d2);
          d1 = __builtin_amdgcn_fmed3f(d, d0, d1);
          d0 = fminf(d, d0);
        }
        {
          const float d = dp.y; const int m = jb * 16 + 2 * e + 1;
          const bool c0 = d < d0, c1 = d < d1, c2 = d < d2;
          i2 = c1 ? i1 : (c2 ? m : i2);
          i1 = c0 ? i0 : (c1 ? m : i1);
          i0 = c0 ? m : i0;
          d2 = __builtin_amdgcn_fmed3f(d, d1, d2);
          d1 = __builtin_amdgcn_fmed3f(d, d0, d1);
          d0 = fminf(d, d0);
        }
      }
    }
    i0 += sub * 64; i1 += sub * 64; i2 += sub * 64;   // local -> global idx
  }

  // ---- stable butterfly merge over 16 subs (lower sub = lower index range) ----
#pragma unroll
  for (int mk = 1; mk <= 8; mk <<= 1) {
    const float pd0 = __shfl_xor(d0, mk), pd1 = __shfl_xor(d1, mk), pd2 = __shfl_xor(d2, mk);
    const int   pi0 = __shfl_xor(i0, mk), pi1 = __shfl_xor(i1, mk), pi2 = __shfl_xor(i2, mk);
    const bool lo = (sub & mk) == 0;
    const float a0 = lo ? d0 : pd0, a1 = lo ? d1 : pd1, a2 = lo ? d2 : pd2;
    const float b0 = lo ? pd0 : d0, b1v = lo ? pd1 : d1, b2v = lo ? pd2 : d2;
    const int   A0 = lo ? i0 : pi0, A1 = lo ? i1 : pi1, A2 = lo ? i2 : pi2;
    const int   B0 = lo ? pi0 : i0, B1 = lo ? pi1 : i1, B2 = lo ? pi2 : i2;
    const bool c0 = b0 < a0;             // strict: a wins ties (lower indices)
    const bool cb1a0 = b1v < a0, cb0a1 = b0 < a1;
    const bool cb1a1 = b1v < a1, cb2a0 = b2v < a0, cb0a2 = b0 < a2;
    const float m0 = c0 ? b0 : a0;                 const int M0 = c0 ? B0 : A0;
    const float t1a = cb1a0 ? b1v : a0;            const int T1a = cb1a0 ? B1 : A0;
    const float t1b = cb0a1 ? b0 : a1;             const int T1b = cb0a1 ? B0 : A1;
    const float m1 = c0 ? t1a : t1b;               const int M1 = c0 ? T1a : T1b;
    const float sA = cb2a0 ? b2v : a0;             const int SA = cb2a0 ? B2 : A0;
    const float sB = cb1a1 ? b1v : a1;             const int SB = cb1a1 ? B1 : A1;
    const float sD = cb0a2 ? b0 : a2;              const int SD = cb0a2 ? B0 : A2;
    const float m2 = c0 ? (cb1a0 ? sA : sB) : (cb0a1 ? sB : sD);
    const int   M2 = c0 ? (cb1a0 ? SA : SB) : (cb0a1 ? SB : SD);
    d0 = m0; d1 = m1; d2 = m2; i0 = M0; i1 = M1; i2 = M2;
  }

  if (sub == 0) {
    const float t0 = sqrtf(fmaxf(d0, 0.f)), t1 = sqrtf(fmaxf(d1, 0.f)),
                t2 = sqrtf(fmaxf(d2, 0.f));
    const float r0 = 1.0f / (t0 + 1e-8f), r1 = 1.0f / (t1 + 1e-8f),
                r2 = 1.0f / (t2 + 1e-8f);
    const float rs = __fadd_rn(__fadd_rn(r0, r1), r2);
    const size_t base = ((size_t)b * N_PTS + gn) * 3;
    idx3[base + 0] = i0; idx3[base + 1] = i1; idx3[base + 2] = i2;
    w3[base + 0] = r0 / rs; w3[base + 1] = r1 / rs; w3[base + 2] = r2 / rs;
  }
}

// ---------------------------------------------------------------------------
// Build + GEMM kernel per 32-query tile, 256 threads / 4 waves, LDS ~25 KB
// (hbuf aliases pfB low half after a barrier). r10's build/GEMM verbatim,
// idx/w sourced from global (r2 pattern).
// ---------------------------------------------------------------------------
__global__ __launch_bounds__(256, 4) void gemm_k(
    const float* __restrict__ featsT,   // (BS, M, C0) f32
    const float* __restrict__ skip,     // (BS, C1, N) f32
    const ushort* __restrict__ W1f,
    const float* __restrict__ b1,
    const ushort* __restrict__ W2f,
    const float* __restrict__ b2,
    const int* __restrict__ idx3, const float* __restrict__ w3,
    float* __restrict__ out) {          // (BS, C2, N) f32
  __shared__ ushort pfB[12288];                   // 384x32 bf16, swizzled frag order
  __shared__ int   idx_s[32][3];
  __shared__ float w_s[32][3];
  ushort* hbuf = pfB;                             // alias (after barrier 3)

  const int t  = threadIdx.x;
  const int b  = blockIdx.x & 7;                  // XCD-pinned batch
  const int n0 = (blockIdx.x >> 3) * 32;
  const int wv = t >> 6, l = t & 63;

  if (t < 96) {
    const int j = t / 3, k = t - 3 * j;
    const size_t gg = ((size_t)b * N_PTS + n0 + j) * 3 + k;
    idx_s[j][k] = idx3[gg];
    w_s[j][k]   = w3[gg];
  }
  __syncthreads();   // barrier 1: idx/w staged

  // ---- build rows 0..255: interp feats, row-coalesced ----
  {
    const float* fb = featsT + (size_t)b * M_PTS * C0;
#pragma unroll
    for (int qi = 0; qi < 8; ++qi) {
      const int nq = wv * 8 + qi;
      const int  j0 = idx_s[nq][0], j1 = idx_s[nq][1], j2 = idx_s[nq][2];
      const float w0 = w_s[nq][0], w1 = w_s[nq][1], w2 = w_s[nq][2];
      const float4 f0 = *(const float4*)(fb + (size_t)j0 * C0 + l * 4);
      const float4 f1 = *(const float4*)(fb + (size_t)j1 * C0 + l * 4);
      const float4 f2 = *(const float4*)(fb + (size_t)j2 * C0 + l * 4);
      ushort4 hv;
      hv.x = f2bf(w0 * f0.x + w1 * f1.x + w2 * f2.x);
      hv.y = f2bf(w0 * f0.y + w1 * f1.y + w2 * f2.y);
      hv.z = f2bf(w0 * f0.z + w1 * f1.z + w2 * f2.z);
      hv.w = f2bf(w0 * f0.w + w1 * f1.w + w2 * f2.w);
      const int kq = l >> 1;
      const int u = kq * 32 + (nq ^ (kq & 7));
      *reinterpret_cast<ushort4*>(&pfB[u * 8 + (l & 1) * 4]) = hv;
    }
  }
  // ---- rows 256..383: skip feats ----
#pragma unroll
  for (int it = 0; it < 8; ++it) {
    const int id = t + it * 256;
    const int r2 = id >> 5, nn = id & 31;
    const float s0v = skip[((size_t)b * C1 + 2 * r2 + 0) * N_PTS + n0 + nn];
    const float s1v = skip[((size_t)b * C1 + 2 * r2 + 1) * N_PTS + n0 + nn];
    const int k = C0 + 2 * r2;
    const int kq = k >> 3;
    const int u = kq * 32 + (nn ^ (kq & 7));
    ushort2 sv; sv.x = f2bf(s0v); sv.y = f2bf(s1v);
    *reinterpret_cast<ushort2*>(&pfB[u * 8 + (k & 7)]) = sv;
  }
  __syncthreads();   // barrier 2: pfB complete

  const int c = l & 15, g = l >> 4;

  f32x4 acc[4][2];
#pragma unroll
  for (int i = 0; i < 4; ++i)
#pragma unroll
    for (int j = 0; j < 2; ++j) acc[i][j] = (f32x4){0.f, 0.f, 0.f, 0.f};

  // ---------------- GEMM1: h = relu(W1 @ pf + b1), K = 384 ----------------
  for (int kb = 0; kb < 12; ++kb) {
    const int kqg = kb * 4 + g;
    bf16x8 bfr[2], afr[4];
#pragma unroll
    for (int j = 0; j < 2; ++j)
      bfr[j] = *reinterpret_cast<const bf16x8*>(&pfB[(kqg * 32 + ((j * 16 + c) ^ (kqg & 7))) * 8]);
#pragma unroll
    for (int i = 0; i < 4; ++i)
      afr[i] = *reinterpret_cast<const bf16x8*>(&W1f[(((wv * 4 + i) * 12 + kb) * 4 + g) * 128 + c * 8]);
    __builtin_amdgcn_s_setprio(1);
#pragma unroll
    for (int i = 0; i < 4; ++i)
#pragma unroll
      for (int j = 0; j < 2; ++j)
        acc[i][j] = __builtin_amdgcn_mfma_f32_16x16x32_bf16(afr[i], bfr[j], acc[i][j], 0, 0, 0);
    __builtin_amdgcn_s_setprio(0);
  }
  __syncthreads();   // barrier 3: all pfB reads done (hbuf aliases pfB)

  // h -> hbuf (bf16, swizzled frag order)
#pragma unroll
  for (int i = 0; i < 4; ++i) {
    const int mbase = wv * 64 + i * 16 + g * 4;
    const float4 bias = *(const float4*)(b1 + mbase);
#pragma unroll
    for (int j = 0; j < 2; ++j) {
      const int nn = j * 16 + c;
      const int kq = mbase >> 3;
      const int u = kq * 32 + (nn ^ (kq & 7));
      ushort4 hv;
      hv.x = f2bf(fmaxf(acc[i][j].x + bias.x, 0.f));
      hv.y = f2bf(fmaxf(acc[i][j].y + bias.y, 0.f));
      hv.z = f2bf(fmaxf(acc[i][j].z + bias.z, 0.f));
      hv.w = f2bf(fmaxf(acc[i][j].w + bias.w, 0.f));
      *reinterpret_cast<ushort4*>(&hbuf[u * 8 + (mbase & 7)]) = hv;
    }
  }
  __syncthreads();   // barrier 4: h complete

#pragma unroll
  for (int i = 0; i < 4; ++i)
#pragma unroll
    for (int j = 0; j < 2; ++j) acc[i][j] = (f32x4){0.f, 0.f, 0.f, 0.f};

  // ---------------- GEMM2: out = relu(W2 @ h + b2), K = 256 ----------------
  for (int kb = 0; kb < 8; ++kb) {
    const int kqg = kb * 4 + g;
    bf16x8 bfr[2], afr[4];
#pragma unroll
    for (int j = 0; j < 2; ++j)
      bfr[j] = *reinterpret_cast<const bf16x8*>(&hbuf[(kqg * 32 + ((j * 16 + c) ^ (kqg & 7))) * 8]);
#pragma unroll
    for (int i = 0; i < 4; ++i)
      afr[i] = *reinterpret_cast<const bf16x8*>(&W2f[(((wv * 4 + i) * 8 + kb) * 4 + g) * 128 + c * 8]);
    __builtin_amdgcn_s_setprio(1);
#pragma unroll
    for (int i = 0; i < 4; ++i)
#pragma unroll
      for (int j = 0; j < 2; ++j)
        acc[i][j] = __builtin_amdgcn_mfma_f32_16x16x32_bf16(afr[i], bfr[j], acc[i][j], 0, 0, 0);
    __builtin_amdgcn_s_setprio(0);
  }

  // epilogue: relu(acc + b2) -> out
#pragma unroll
  for (int i = 0; i < 4; ++i) {
    const int mbase = wv * 64 + i * 16 + g * 4;
    const float4 bias = *(const float4*)(b2 + mbase);
#pragma unroll
    for (int j = 0; j < 2; ++j) {
      const int nn = n0 + j * 16 + c;
      out[((size_t)b * C2 + mbase + 0) * N_PTS + nn] = fmaxf(acc[i][j].x + bias.x, 0.f);
      out[((size_t)b * C2 + mbase + 1) * N_PTS + nn] = fmaxf(acc[i][j].y + bias.y, 0.f);
      out[((size_t)b * C2 + mbase + 2) * N_PTS + nn] = fmaxf(acc[i][j].z + bias.z, 0.f);
      out[((size_t)b * C2 + mbase + 3) * N_PTS + nn] = fmaxf(acc[i][j].w + bias.w, 0.f);
    }
  }
}

// ---------------------------------------------------------------------------
extern "C" void kernel_launch(void* const* d_in, const int* in_sizes, int n_in,
                              void* d_out, int out_size, void* d_ws, size_t ws_size,
                              hipStream_t stream) {
  const float* xyz   = (const float*)d_in[0];
  const float* pxyz  = (const float*)d_in[1];
  const float* feats = (const float*)d_in[2];
  const float* skip  = (const float*)d_in[3];
  const float* W1    = (const float*)d_in[4];
  const float* b1    = (const float*)d_in[5];
  const float* W2    = (const float*)d_in[6];
  const float* b2    = (const float*)d_in[7];
  float* out = (float*)d_out;

  float*  ws     = (float*)d_ws;
  float*  featsT = ws;                                           // 8*1024*256 f32
  ushort* W1f    = (ushort*)(featsT + (size_t)BS * M_PTS * C0);  // 98304 ushort
  ushort* W2f    = W1f + (size_t)C2 * K1DIM;                     // 65536 ushort
  int*    idx3   = (int*)(W2f + (size_t)C2 * C2);                // 8*4096*3 i32
  float*  w3     = (float*)(idx3 + (size_t)BS * N_PTS * 3);      // 8*4096*3 f32

  nn_scan_k<<<BS * (N_PTS / 16), 256, 0, stream>>>(xyz, pxyz, idx3, w3);
  prep_k<<<2432, 256, 0, stream>>>(feats, W1, W2, featsT, W1f, W2f);
  gemm_k<<<BS * (N_PTS / 32), 256, 0, stream>>>(featsT, skip, W1f, b1, W2f, b2,
                                                idx3, w3, out);
}

// Round 12
// 48.418 us; speedup vs baseline: 1.2051x; 1.2051x over previous
//
#include <hip/hip_runtime.h>
#include <hip/hip_bf16.h>
#include <cstddef>
#include <cstdint>

#define BS    8
#define M_PTS 1024
#define N_PTS 4096
#define C0    256
#define C1    128
#define C2    256
#define K1DIM 384   // C0 + C1

typedef __attribute__((ext_vector_type(8))) short bf16x8;
typedef __attribute__((ext_vector_type(4))) float f32x4;
typedef __attribute__((ext_vector_type(2))) float f32x2;

__device__ __forceinline__ ushort f2bf(float f) {
  union { float f; unsigned u; } v; v.f = f;
  unsigned r = v.u + 0x7fffu + ((v.u >> 16) & 1u);   // RNE
  return (ushort)(r >> 16);
}

__device__ __forceinline__ float rdlane_f(float v, int lane) {
  union { float f; int i; } u; u.f = v;
  u.i = __builtin_amdgcn_readlane(u.i, lane);
  return u.f;
}

// packed fp32; per-half rounding identical to v_mul/v_add (validated r7/r10)
__device__ __forceinline__ f32x2 pk_mul(f32x2 a, f32x2 b) {
  f32x2 r; asm("v_pk_mul_f32 %0, %1, %2" : "=v"(r) : "v"(a), "v"(b)); return r;
}
__device__ __forceinline__ f32x2 pk_add(f32x2 a, f32x2 b) {
  f32x2 r; asm("v_pk_add_f32 %0, %1, %2" : "=v"(r) : "v"(a), "v"(b)); return r;
}

// exact stable 3+3 merge, butterfly over 16 sub-lanes (r10 formula, 4 stages)
__device__ __forceinline__ void merge16(float& d0, float& d1, float& d2,
                                        int& i0, int& i1, int& i2, int sub) {
#pragma unroll
  for (int mk = 1; mk <= 8; mk <<= 1) {
    const float pd0 = __shfl_xor(d0, mk), pd1 = __shfl_xor(d1, mk), pd2 = __shfl_xor(d2, mk);
    const int   pi0 = __shfl_xor(i0, mk), pi1 = __shfl_xor(i1, mk), pi2 = __shfl_xor(i2, mk);
    const bool lo = (sub & mk) == 0;
    const float a0 = lo ? d0 : pd0, a1 = lo ? d1 : pd1, a2 = lo ? d2 : pd2;
    const float b0 = lo ? pd0 : d0, b1v = lo ? pd1 : d1, b2v = lo ? pd2 : d2;
    const int   A0 = lo ? i0 : pi0, A1 = lo ? i1 : pi1, A2 = lo ? i2 : pi2;
    const int   B0 = lo ? pi0 : i0, B1 = lo ? pi1 : i1, B2 = lo ? pi2 : i2;
    const bool c0 = b0 < a0;             // strict: a wins ties (lower indices)
    const bool cb1a0 = b1v < a0, cb0a1 = b0 < a1;
    const bool cb1a1 = b1v < a1, cb2a0 = b2v < a0, cb0a2 = b0 < a2;
    const float m0 = c0 ? b0 : a0;                 const int M0 = c0 ? B0 : A0;
    const float t1a = cb1a0 ? b1v : a0;            const int T1a = cb1a0 ? B1 : A0;
    const float t1b = cb0a1 ? b0 : a1;             const int T1b = cb0a1 ? B0 : A1;
    const float m1 = c0 ? t1a : t1b;               const int M1 = c0 ? T1a : T1b;
    const float sA = cb2a0 ? b2v : a0;             const int SA = cb2a0 ? B2 : A0;
    const float sB = cb1a1 ? b1v : a1;             const int SB = cb1a1 ? B1 : A1;
    const float sD = cb0a2 ? b0 : a2;              const int SD = cb0a2 ? B0 : A2;
    const float m2 = c0 ? (cb1a0 ? sA : sB) : (cb0a1 ? sB : sD);
    const int   M2 = c0 ? (cb1a0 ? SA : SB) : (cb0a1 ? SB : SD);
    d0 = m0; d1 = m1; d2 = m2; i0 = M0; i1 = M1; i2 = M2;
  }
}

// ---------------------------------------------------------------------------
// Merged prep: blocks [0,2048) transpose feats (BS,C0,M)->(BS,M,C0);
// blocks [2048,2432) convert W1/W2 to bf16 MFMA A-fragment order
// ---------------------------------------------------------------------------
__global__ __launch_bounds__(256) void prep_k(
    const float* __restrict__ feats, const float* __restrict__ W1,
    const float* __restrict__ W2, float* __restrict__ featsT,
    ushort* __restrict__ W1f, ushort* __restrict__ W2f) {
  __shared__ float tile[32][33];
  const int t = threadIdx.x;
  if (blockIdx.x < 2048) {
    const int bx = blockIdx.x & 31;          // M tile
    const int by = (blockIdx.x >> 5) & 7;    // C0 tile
    const int bz = blockIdx.x >> 8;          // batch
    const int tx = t & 31, ty = t >> 5;
    const float* ip = feats + (size_t)bz * C0 * M_PTS;
    float*       op = featsT + (size_t)bz * C0 * M_PTS;
    const int r0 = by * 32, c0 = bx * 32;
#pragma unroll
    for (int i = 0; i < 4; ++i)
      tile[ty + i * 8][tx] = ip[(size_t)(r0 + ty + i * 8) * M_PTS + c0 + tx];
    __syncthreads();
#pragma unroll
    for (int i = 0; i < 4; ++i)
      op[(size_t)(c0 + ty + i * 8) * C0 + r0 + tx] = tile[tx][ty + i * 8];
  } else {
    const int id = (blockIdx.x - 2048) * 256 + t;
    if (id < C2 * K1DIM) {
      int m = id / K1DIM, k = id - m * K1DIM;
      int off = (((m >> 4) * 12 + (k >> 5)) * 4 + ((k >> 3) & 3)) * 128 + (m & 15) * 8 + (k & 7);
      W1f[off] = f2bf(W1[id]);
    }
    if (id < C2 * C2) {
      int m = id >> 8, k = id & 255;
      int off = (((m >> 4) * 8 + (k >> 5)) * 4 + ((k >> 3) & 3)) * 128 + (m & 15) * 8 + (k & 7);
      W2f[off] = f2bf(W2[id]);
    }
  }
}

// ---------------------------------------------------------------------------
// Fully fused per 32-query tile, 256 threads / 4 waves, LDS exactly 40960 B.
// Scan: 16 subs x 32 pairs, each lane computes distances for TWO queries
// (qp and qp+16) per pair-read -> LDS instr halved vs r10. Points stored as
// split SoA arrays loA/hiA with swizzle U = p ^ ((p>>5)&7): 2-way banks.
// Build wave wv owns columns {4wv..4wv+3, 16+4wv..19+4wv} (wave-local
// readlane). Selection/merge/weights arithmetic byte-identical to r10.
// ---------------------------------------------------------------------------
__global__ __launch_bounds__(256, 4) void fp_fused_k(
    const float* __restrict__ xyz,      // (BS, M, 3)
    const float* __restrict__ pxyz,     // (BS, N, 3)
    const float* __restrict__ featsT,   // (BS, M, C0) f32
    const float* __restrict__ skip,     // (BS, C1, N) f32
    const ushort* __restrict__ W1f,
    const float* __restrict__ b1,
    const ushort* __restrict__ W2f,
    const float* __restrict__ b2,
    float* __restrict__ out) {          // (BS, C2, N) f32
  __shared__ float4 smemq[2560];                  // 40960 B total
  float4* loAr = smemq;                           // [512] {x0,x1,y0,y1}
  float4* hiAr = smemq + 512;                     // [512] {z0,z1,s0,s1}
  ushort* pfB  = (ushort*)(smemq + 1024);         // [12288] 384x32 bf16 frag order
  ushort* hbuf = (ushort*)smemq;                  // [8192] 256x32 bf16 (aliases loA/hiA)

  const int t  = threadIdx.x;
  const int b  = blockIdx.x & 7;                  // XCD-pinned batch
  const int n0 = (blockIdx.x >> 3) * 32;
  const int wv = t >> 6, l = t & 63;
  const int qp = t >> 4, sub = t & 15;

  // two queries per lane
  const float qxa = pxyz[((size_t)b * N_PTS + n0 + qp) * 3 + 0];
  const float qya = pxyz[((size_t)b * N_PTS + n0 + qp) * 3 + 1];
  const float qza = pxyz[((size_t)b * N_PTS + n0 + qp) * 3 + 2];
  const float qxb = pxyz[((size_t)b * N_PTS + n0 + qp + 16) * 3 + 0];
  const float qyb = pxyz[((size_t)b * N_PTS + n0 + qp + 16) * 3 + 1];
  const float qzb = pxyz[((size_t)b * N_PTS + n0 + qp + 16) * 3 + 2];

  // ---- stage 2 SoA-pairs per thread, split arrays, slot U = p ^ ((p>>5)&7) ----
#pragma unroll
  for (int it = 0; it < 2; ++it) {
    const int p = t + it * 256;                   // pair index 0..511
    const float2* xb = (const float2*)(xyz + (size_t)b * 3 * M_PTS + 6 * p);
    const float2 A = xb[0], B = xb[1], C = xb[2];
    const float x0 = A.x, y0 = A.y, z0 = B.x, x1 = B.y, y1 = C.x, z1 = C.y;
    const float s0 = __fadd_rn(__fadd_rn(__fmul_rn(x0, x0), __fmul_rn(y0, y0)),
                               __fmul_rn(z0, z0));
    const float s1 = __fadd_rn(__fadd_rn(__fmul_rn(x1, x1), __fmul_rn(y1, y1)),
                               __fmul_rn(z1, z1));
    const int U = p ^ ((p >> 5) & 7);
    loAr[U] = (float4){x0, x1, y0, y1};
    hiAr[U] = (float4){z0, z1, s0, s1};
  }

  // ---- skip prefetch into registers (HBM latency hides under the scan) ----
  float skp[16];
#pragma unroll
  for (int it = 0; it < 8; ++it) {
    const int id = t + it * 256;
    const int r2 = id >> 5, nn = id & 31;
    skp[2 * it + 0] = skip[((size_t)b * C1 + 2 * r2 + 0) * N_PTS + n0 + nn];
    skp[2 * it + 1] = skip[((size_t)b * C1 + 2 * r2 + 1) * N_PTS + n0 + nn];
  }

  const float qqa = __fadd_rn(__fadd_rn(__fmul_rn(qxa, qxa), __fmul_rn(qya, qya)),
                              __fmul_rn(qza, qza));
  const float qqb = __fadd_rn(__fadd_rn(__fmul_rn(qxb, qxb), __fmul_rn(qyb, qyb)),
                              __fmul_rn(qzb, qzb));
  __syncthreads();   // barrier 1: pts staged

  // ---- scan: 16 subs x 32 pairs; 2 queries per lane per pair-read ----
  float dA0 = 3.4e38f, dA1 = 3.4e38f, dA2 = 3.4e38f;
  float dB0 = 3.4e38f, dB1 = 3.4e38f, dB2 = 3.4e38f;
  int   iA0 = 0, iA1 = 0, iA2 = 0, iB0 = 0, iB1 = 0, iB2 = 0;
  {
    const f32x2 QxA = {qxa, qxa}, QyA = {qya, qya}, QzA = {qza, qza}, QqA = {qqa, qqa};
    const f32x2 QxB = {qxb, qxb}, QyB = {qyb, qyb}, QzB = {qzb, qzb}, QqB = {qqb, qqb};
    const f32x2 Mn2 = {-2.0f, -2.0f};
    const int base = sub * 32, sx = sub & 7;
#pragma unroll
    for (int jb = 0; jb < 4; ++jb) {
#pragma unroll
      for (int e = 0; e < 8; ++e) {
        const int slot = base + jb * 8 + (e ^ sx);   // holds pair p = base+jb*8+e
        const float4 lo = loAr[slot];
        const float4 hi = hiAr[slot];
        const f32x2 Xp = {lo.x, lo.y}, Yp = {lo.z, lo.w};
        const f32x2 Zp = {hi.x, hi.y}, Sp = {hi.z, hi.w};
        const int ml = jb * 16 + 2 * e;
        {
          const f32x2 dotp = pk_add(pk_add(pk_mul(QxA, Xp), pk_mul(QyA, Yp)),
                                    pk_mul(QzA, Zp));
          const f32x2 dp = pk_add(pk_add(QqA, pk_mul(dotp, Mn2)), Sp);
          {
            const float d = dp.x; const int m = ml;
            const bool c0 = d < dA0, c1 = d < dA1, c2 = d < dA2;
            iA2 = c1 ? iA1 : (c2 ? m : iA2);
            iA1 = c0 ? iA0 : (c1 ? m : iA1);
            iA0 = c0 ? m : iA0;
            dA2 = __builtin_amdgcn_fmed3f(d, dA1, dA2);
            dA1 = __builtin_amdgcn_fmed3f(d, dA0, dA1);
            dA0 = fminf(d, dA0);
          }
          {
            const float d = dp.y; const int m = ml + 1;
            const bool c0 = d < dA0, c1 = d < dA1, c2 = d < dA2;
            iA2 = c1 ? iA1 : (c2 ? m : iA2);
            iA1 = c0 ? iA0 : (c1 ? m : iA1);
            iA0 = c0 ? m : iA0;
            dA2 = __builtin_amdgcn_fmed3f(d, dA1, dA2);
            dA1 = __builtin_amdgcn_fmed3f(d, dA0, dA1);
            dA0 = fminf(d, dA0);
          }
        }
        {
          const f32x2 dotp = pk_add(pk_add(pk_mul(QxB, Xp), pk_mul(QyB, Yp)),
                                    pk_mul(QzB, Zp));
          const f32x2 dp = pk_add(pk_add(QqB, pk_mul(dotp, Mn2)), Sp);
          {
            const float d = dp.x; const int m = ml;
            const bool c0 = d < dB0, c1 = d < dB1, c2 = d < dB2;
            iB2 = c1 ? iB1 : (c2 ? m : iB2);
            iB1 = c0 ? iB0 : (c1 ? m : iB1);
            iB0 = c0 ? m : iB0;
            dB2 = __builtin_amdgcn_fmed3f(d, dB1, dB2);
            dB1 = __builtin_amdgcn_fmed3f(d, dB0, dB1);
            dB0 = fminf(d, dB0);
          }
          {
            const float d = dp.y; const int m = ml + 1;
            const bool c0 = d < dB0, c1 = d < dB1, c2 = d < dB2;
            iB2 = c1 ? iB1 : (c2 ? m : iB2);
            iB1 = c0 ? iB0 : (c1 ? m : iB1);
            iB0 = c0 ? m : iB0;
            dB2 = __builtin_amdgcn_fmed3f(d, dB1, dB2);
            dB1 = __builtin_amdgcn_fmed3f(d, dB0, dB1);
            dB0 = fminf(d, dB0);
          }
        }
      }
    }
    iA0 += sub * 64; iA1 += sub * 64; iA2 += sub * 64;   // local -> global idx
    iB0 += sub * 64; iB1 += sub * 64; iB2 += sub * 64;
  }

  // ---- stable butterfly merges over 16 subs ----
  merge16(dA0, dA1, dA2, iA0, iA1, iA2, sub);
  merge16(dB0, dB1, dB2, iB0, iB1, iB2, sub);

  // ---- interpolation weights for both queries ----
  float wA0, wA1, wA2, wB0, wB1, wB2;
  {
    const float t0 = sqrtf(fmaxf(dA0, 0.f)), t1 = sqrtf(fmaxf(dA1, 0.f)),
                t2 = sqrtf(fmaxf(dA2, 0.f));
    const float r0 = 1.0f / (t0 + 1e-8f), r1 = 1.0f / (t1 + 1e-8f),
                r2 = 1.0f / (t2 + 1e-8f);
    const float rs = __fadd_rn(__fadd_rn(r0, r1), r2);
    wA0 = r0 / rs; wA1 = r1 / rs; wA2 = r2 / rs;
  }
  {
    const float t0 = sqrtf(fmaxf(dB0, 0.f)), t1 = sqrtf(fmaxf(dB1, 0.f)),
                t2 = sqrtf(fmaxf(dB2, 0.f));
    const float r0 = 1.0f / (t0 + 1e-8f), r1 = 1.0f / (t1 + 1e-8f),
                r2 = 1.0f / (t2 + 1e-8f);
    const float rs = __fadd_rn(__fadd_rn(r0, r1), r2);
    wB0 = r0 / rs; wB1 = r1 / rs; wB2 = r2 / rs;
  }

  // ---- build rows 0..255: wave wv builds its own 8 columns (wave-local) ----
  {
    const float* fb = featsT + (size_t)b * M_PTS * C0;
#pragma unroll
    for (int qi = 0; qi < 8; ++qi) {
      const int src = (qi & 3) * 16;     // lane with qp = wv*4 + (qi&3)
      int j0, j1, j2; float w0, w1, w2;
      if (qi < 4) {
        j0 = __builtin_amdgcn_readlane(iA0, src);
        j1 = __builtin_amdgcn_readlane(iA1, src);
        j2 = __builtin_amdgcn_readlane(iA2, src);
        w0 = rdlane_f(wA0, src); w1 = rdlane_f(wA1, src); w2 = rdlane_f(wA2, src);
      } else {
        j0 = __builtin_amdgcn_readlane(iB0, src);
        j1 = __builtin_amdgcn_readlane(iB1, src);
        j2 = __builtin_amdgcn_readlane(iB2, src);
        w0 = rdlane_f(wB0, src); w1 = rdlane_f(wB1, src); w2 = rdlane_f(wB2, src);
      }
      const int nq = wv * 4 + (qi & 3) + ((qi >> 2) << 4);
      const float4 f0 = *(const float4*)(fb + (size_t)j0 * C0 + l * 4);
      const float4 f1 = *(const float4*)(fb + (size_t)j1 * C0 + l * 4);
      const float4 f2 = *(const float4*)(fb + (size_t)j2 * C0 + l * 4);
      ushort4 hv;
      hv.x = f2bf(w0 * f0.x + w1 * f1.x + w2 * f2.x);
      hv.y = f2bf(w0 * f0.y + w1 * f1.y + w2 * f2.y);
      hv.z = f2bf(w0 * f0.z + w1 * f1.z + w2 * f2.z);
      hv.w = f2bf(w0 * f0.w + w1 * f1.w + w2 * f2.w);
      const int kq = l >> 1;
      const int u = kq * 32 + (nq ^ (kq & 7));
      *reinterpret_cast<ushort4*>(&pfB[u * 8 + (l & 1) * 4]) = hv;
    }
  }
  // ---- rows 256..383: skip feats from prefetch registers ----
#pragma unroll
  for (int it = 0; it < 8; ++it) {
    const int id = t + it * 256;
    const int r2 = id >> 5, nn = id & 31;
    const int k = C0 + 2 * r2;
    const int kq = k >> 3;
    const int u = kq * 32 + (nn ^ (kq & 7));
    ushort2 sv; sv.x = f2bf(skp[2 * it]); sv.y = f2bf(skp[2 * it + 1]);
    *reinterpret_cast<ushort2*>(&pfB[u * 8 + (k & 7)]) = sv;
  }
  __syncthreads();   // barrier 2: pfB complete (all scans done too)

  const int c = l & 15, g = l >> 4;

  f32x4 acc[4][2];
#pragma unroll
  for (int i = 0; i < 4; ++i)
#pragma unroll
    for (int j = 0; j < 2; ++j) acc[i][j] = (f32x4){0.f, 0.f, 0.f, 0.f};

  // ---------------- GEMM1: h = relu(W1 @ pf + b1), K = 384 ----------------
  for (int kb = 0; kb < 12; ++kb) {
    const int kqg = kb * 4 + g;
    bf16x8 bfr[2], afr[4];
#pragma unroll
    for (int j = 0; j < 2; ++j)
      bfr[j] = *reinterpret_cast<const bf16x8*>(&pfB[(kqg * 32 + ((j * 16 + c) ^ (kqg & 7))) * 8]);
#pragma unroll
    for (int i = 0; i < 4; ++i)
      afr[i] = *reinterpret_cast<const bf16x8*>(&W1f[(((wv * 4 + i) * 12 + kb) * 4 + g) * 128 + c * 8]);
    __builtin_amdgcn_s_setprio(1);
#pragma unroll
    for (int i = 0; i < 4; ++i)
#pragma unroll
      for (int j = 0; j < 2; ++j)
        acc[i][j] = __builtin_amdgcn_mfma_f32_16x16x32_bf16(afr[i], bfr[j], acc[i][j], 0, 0, 0);
    __builtin_amdgcn_s_setprio(0);
  }

  // h -> hbuf (old pts region; dead after barrier 2 — no barrier needed)
#pragma unroll
  for (int i = 0; i < 4; ++i) {
    const int mbase = wv * 64 + i * 16 + g * 4;
    const float4 bias = *(const float4*)(b1 + mbase);
#pragma unroll
    for (int j = 0; j < 2; ++j) {
      const int nn = j * 16 + c;
      const int kq = mbase >> 3;
      const int u = kq * 32 + (nn ^ (kq & 7));
      ushort4 hv;
      hv.x = f2bf(fmaxf(acc[i][j].x + bias.x, 0.f));
      hv.y = f2bf(fmaxf(acc[i][j].y + bias.y, 0.f));
      hv.z = f2bf(fmaxf(acc[i][j].z + bias.z, 0.f));
      hv.w = f2bf(fmaxf(acc[i][j].w + bias.w, 0.f));
      *reinterpret_cast<ushort4*>(&hbuf[u * 8 + (mbase & 7)]) = hv;
    }
  }
  __syncthreads();   // barrier 3: h complete

#pragma unroll
  for (int i = 0; i < 4; ++i)
#pragma unroll
    for (int j = 0; j < 2; ++j) acc[i][j] = (f32x4){0.f, 0.f, 0.f, 0.f};

  // ---------------- GEMM2: out = relu(W2 @ h + b2), K = 256 ----------------
  for (int kb = 0; kb < 8; ++kb) {
    const int kqg = kb * 4 + g;
    bf16x8 bfr[2], afr[4];
#pragma unroll
    for (int j = 0; j < 2; ++j)
      bfr[j] = *reinterpret_cast<const bf16x8*>(&hbuf[(kqg * 32 + ((j * 16 + c) ^ (kqg & 7))) * 8]);
#pragma unroll
    for (int i = 0; i < 4; ++i)
      afr[i] = *reinterpret_cast<const bf16x8*>(&W2f[(((wv * 4 + i) * 8 + kb) * 4 + g) * 128 + c * 8]);
    __builtin_amdgcn_s_setprio(1);
#pragma unroll
    for (int i = 0; i < 4; ++i)
#pragma unroll
      for (int j = 0; j < 2; ++j)
        acc[i][j] = __builtin_amdgcn_mfma_f32_16x16x32_bf16(afr[i], bfr[j], acc[i][j], 0, 0, 0);
    __builtin_amdgcn_s_setprio(0);
  }

  // epilogue: relu(acc + b2) -> out
#pragma unroll
  for (int i = 0; i < 4; ++i) {
    const int mbase = wv * 64 + i * 16 + g * 4;
    const float4 bias = *(const float4*)(b2 + mbase);
#pragma unroll
    for (int j = 0; j < 2; ++j) {
      const int nn = n0 + j * 16 + c;
      out[((size_t)b * C2 + mbase + 0) * N_PTS + nn] = fmaxf(acc[i][j].x + bias.x, 0.f);
      out[((size_t)b * C2 + mbase + 1) * N_PTS + nn] = fmaxf(acc[i][j].y + bias.y, 0.f);
      out[((size_t)b * C2 + mbase + 2) * N_PTS + nn] = fmaxf(acc[i][j].z + bias.z, 0.f);
      out[((size_t)b * C2 + mbase + 3) * N_PTS + nn] = fmaxf(acc[i][j].w + bias.w, 0.f);
    }
  }
}

// ---------------------------------------------------------------------------
extern "C" void kernel_launch(void* const* d_in, const int* in_sizes, int n_in,
                              void* d_out, int out_size, void* d_ws, size_t ws_size,
                              hipStream_t stream) {
  const float* xyz   = (const float*)d_in[0];
  const float* pxyz  = (const float*)d_in[1];
  const float* feats = (const float*)d_in[2];
  const float* skip  = (const float*)d_in[3];
  const float* W1    = (const float*)d_in[4];
  const float* b1    = (const float*)d_in[5];
  const float* W2    = (const float*)d_in[6];
  const float* b2    = (const float*)d_in[7];
  float* out = (float*)d_out;

  float*  ws     = (float*)d_ws;
  float*  featsT = ws;                                           // 8*1024*256 f32
  ushort* W1f    = (ushort*)(featsT + (size_t)BS * M_PTS * C0);  // 98304 ushort
  ushort* W2f    = W1f + (size_t)C2 * K1DIM;                     // 65536 ushort

  prep_k<<<2432, 256, 0, stream>>>(feats, W1, W2, featsT, W1f, W2f);
  fp_fused_k<<<BS * (N_PTS / 32), 256, 0, stream>>>(xyz, pxyz, featsT, skip,
                                                    W1f, b1, W2f, b2, out);
}

// Round 13
// 46.225 us; speedup vs baseline: 1.2623x; 1.0475x over previous
//
#include <hip/hip_runtime.h>
#include <hip/hip_bf16.h>
#include <cstddef>
#include <cstdint>

#define BS    8
#define M_PTS 1024
#define N_PTS 4096
#define C0    256
#define C1    128
#define C2    256
#define K1DIM 384   // C0 + C1

typedef __attribute__((ext_vector_type(8))) short bf16x8;
typedef __attribute__((ext_vector_type(4))) float f32x4;

__device__ __forceinline__ ushort f2bf(float f) {
  union { float f; unsigned u; } v; v.f = f;
  unsigned r = v.u + 0x7fffu + ((v.u >> 16) & 1u);   // RNE
  return (ushort)(r >> 16);
}
// compiler-friendly bf16 convert (RNE; enables auto v_cvt_pk_bf16_f32 pairing)
__device__ __forceinline__ ushort bf16c(float f) {
  return __builtin_bit_cast(ushort, __float2bfloat16(f));
}

__device__ __forceinline__ float rdlane_f(float v, int lane) {
  union { float f; int i; } u; u.f = v;
  u.i = __builtin_amdgcn_readlane(u.i, lane);
  return u.f;
}

// ---------------------------------------------------------------------------
// Merged prep: blocks [0,2048) transpose feats (BS,C0,M)->(BS,M,C0);
// blocks [2048,2432) convert W1/W2 to bf16 MFMA A-fragment order
// ---------------------------------------------------------------------------
__global__ __launch_bounds__(256) void prep_k(
    const float* __restrict__ feats, const float* __restrict__ W1,
    const float* __restrict__ W2, float* __restrict__ featsT,
    ushort* __restrict__ W1f, ushort* __restrict__ W2f) {
  __shared__ float tile[32][33];
  const int t = threadIdx.x;
  if (blockIdx.x < 2048) {
    const int bx = blockIdx.x & 31;          // M tile
    const int by = (blockIdx.x >> 5) & 7;    // C0 tile
    const int bz = blockIdx.x >> 8;          // batch
    const int tx = t & 31, ty = t >> 5;
    const float* ip = feats + (size_t)bz * C0 * M_PTS;
    float*       op = featsT + (size_t)bz * C0 * M_PTS;
    const int r0 = by * 32, c0 = bx * 32;
#pragma unroll
    for (int i = 0; i < 4; ++i)
      tile[ty + i * 8][tx] = ip[(size_t)(r0 + ty + i * 8) * M_PTS + c0 + tx];
    __syncthreads();
#pragma unroll
    for (int i = 0; i < 4; ++i)
      op[(size_t)(c0 + ty + i * 8) * C0 + r0 + tx] = tile[tx][ty + i * 8];
  } else {
    const int id = (blockIdx.x - 2048) * 256 + t;
    if (id < C2 * K1DIM) {
      int m = id / K1DIM, k = id - m * K1DIM;
      int off = (((m >> 4) * 12 + (k >> 5)) * 4 + ((k >> 3) & 3)) * 128 + (m & 15) * 8 + (k & 7);
      W1f[off] = f2bf(W1[id]);
    }
    if (id < C2 * C2) {
      int m = id >> 8, k = id & 255;
      int off = (((m >> 4) * 8 + (k >> 5)) * 4 + ((k >> 3) & 3)) * 128 + (m & 15) * 8 + (k & 7);
      W2f[off] = f2bf(W2[id]);
    }
  }
}

// ---------------------------------------------------------------------------
// Fully fused per 32-query tile, 256 threads / 4 waves, LDS exactly 40960 B.
// r10 structure; scan distances in plain scalar fp32 (no inline asm); bf16
// converts via __float2bfloat16; build loop 1-deep software-pipelined.
// ---------------------------------------------------------------------------
__global__ __launch_bounds__(256, 4) void fp_fused_k(
    const float* __restrict__ xyz,      // (BS, M, 3)
    const float* __restrict__ pxyz,     // (BS, N, 3)
    const float* __restrict__ featsT,   // (BS, M, C0) f32
    const float* __restrict__ skip,     // (BS, C1, N) f32
    const ushort* __restrict__ W1f,
    const float* __restrict__ b1,
    const ushort* __restrict__ W2f,
    const float* __restrict__ b2,
    float* __restrict__ out) {          // (BS, C2, N) f32
  __shared__ float4 smemq[2560];                  // 40960 B total
  float4* pts4 = smemq;                           // [0,16384): 512 pairs x 32 B
  ushort* pfB  = (ushort*)(smemq + 1024);         // [16384,40960): 384x32 bf16
  ushort* hbuf = (ushort*)smemq;                  // [0,16384): 256x32 bf16 (aliases pts4)

  const int t  = threadIdx.x;
  const int b  = blockIdx.x & 7;                  // XCD-pinned batch
  const int n0 = (blockIdx.x >> 3) * 32;
  const int wv = t >> 6, l = t & 63;
  const int q  = t >> 3, sub = t & 7;

  // query coords (issued early, used in scan)
  const float qx = pxyz[((size_t)b * N_PTS + n0 + q) * 3 + 0];
  const float qy = pxyz[((size_t)b * N_PTS + n0 + q) * 3 + 1];
  const float qz = pxyz[((size_t)b * N_PTS + n0 + q) * 3 + 2];

  // ---- stage 2 SoA-pairs per thread, XOR-staggered slot = p ^ ((p>>6)&7) ----
#pragma unroll
  for (int it = 0; it < 2; ++it) {
    const int p = t + it * 256;                   // pair index 0..511
    const float2* xb = (const float2*)(xyz + (size_t)b * 3 * M_PTS + 6 * p);
    const float2 A = xb[0], B = xb[1], C = xb[2];
    const float x0 = A.x, y0 = A.y, z0 = B.x, x1 = B.y, y1 = C.x, z1 = C.y;
    const float s0 = __fadd_rn(__fadd_rn(__fmul_rn(x0, x0), __fmul_rn(y0, y0)),
                               __fmul_rn(z0, z0));
    const float s1 = __fadd_rn(__fadd_rn(__fmul_rn(x1, x1), __fmul_rn(y1, y1)),
                               __fmul_rn(z1, z1));
    const int U = p ^ ((p >> 6) & 7);
    pts4[U * 2 + 0] = (float4){x0, x1, y0, y1};
    pts4[U * 2 + 1] = (float4){z0, z1, s0, s1};
  }

  // ---- skip prefetch into registers (HBM latency hides under the scan) ----
  float skp[16];
#pragma unroll
  for (int it = 0; it < 8; ++it) {
    const int id = t + it * 256;
    const int r2 = id >> 5, nn = id & 31;
    skp[2 * it + 0] = skip[((size_t)b * C1 + 2 * r2 + 0) * N_PTS + n0 + nn];
    skp[2 * it + 1] = skip[((size_t)b * C1 + 2 * r2 + 1) * N_PTS + n0 + nn];
  }

  const float qq = __fadd_rn(__fadd_rn(__fmul_rn(qx, qx), __fmul_rn(qy, qy)),
                             __fmul_rn(qz, qz));
  __syncthreads();   // barrier 1: pts staged

  // ---- scan: 8 subs x 64 pairs per query; plain scalar distances ----
  float d0 = 3.4e38f, d1 = 3.4e38f, d2 = 3.4e38f;
  int   i0 = 0, i1 = 0, i2 = 0;
  {
    int pe[8];
#pragma unroll
    for (int e = 0; e < 8; ++e) pe[e] = (sub * 64 + (e ^ sub)) * 2;  // de-swizzle
    for (int jb = 0; jb < 8; ++jb) {
#pragma unroll
      for (int e = 0; e < 8; ++e) {
        const float4 A  = pts4[pe[e] + jb * 16];     // {x0,x1,y0,y1}
        const float4 Bv = pts4[pe[e] + jb * 16 + 1]; // {z0,z1,s0,s1}
        {
          const float dot = __fadd_rn(__fadd_rn(__fmul_rn(qx, A.x), __fmul_rn(qy, A.z)),
                                      __fmul_rn(qz, Bv.x));
          const float d = __fadd_rn(__fsub_rn(qq, __fmul_rn(2.0f, dot)), Bv.z);
          const int m = jb * 16 + 2 * e;
          const bool c0 = d < d0, c1 = d < d1, c2 = d < d2;
          i2 = c1 ? i1 : (c2 ? m : i2);
          i1 = c0 ? i0 : (c1 ? m : i1);
          i0 = c0 ? m : i0;
          d2 = __builtin_amdgcn_fmed3f(d, d1, d2);
          d1 = __builtin_amdgcn_fmed3f(d, d0, d1);
          d0 = fminf(d, d0);
        }
        {
          const float dot = __fadd_rn(__fadd_rn(__fmul_rn(qx, A.y), __fmul_rn(qy, A.w)),
                                      __fmul_rn(qz, Bv.y));
          const float d = __fadd_rn(__fsub_rn(qq, __fmul_rn(2.0f, dot)), Bv.w);
          const int m = jb * 16 + 2 * e + 1;
          const bool c0 = d < d0, c1 = d < d1, c2 = d < d2;
          i2 = c1 ? i1 : (c2 ? m : i2);
          i1 = c0 ? i0 : (c1 ? m : i1);
          i0 = c0 ? m : i0;
          d2 = __builtin_amdgcn_fmed3f(d, d1, d2);
          d1 = __builtin_amdgcn_fmed3f(d, d0, d1);
          d0 = fminf(d, d0);
        }
      }
    }
    i0 += sub * 128; i1 += sub * 128; i2 += sub * 128;   // local -> global idx
  }

  // ---- in-register butterfly merge across subs (stable: lower sub wins ties)
#pragma unroll
  for (int mk = 1; mk <= 4; mk <<= 1) {
    const float pd0 = __shfl_xor(d0, mk), pd1 = __shfl_xor(d1, mk), pd2 = __shfl_xor(d2, mk);
    const int   pi0 = __shfl_xor(i0, mk), pi1 = __shfl_xor(i1, mk), pi2 = __shfl_xor(i2, mk);
    const bool lo = (sub & mk) == 0;
    const float a0 = lo ? d0 : pd0, a1 = lo ? d1 : pd1, a2 = lo ? d2 : pd2;
    const float b0 = lo ? pd0 : d0, b1v = lo ? pd1 : d1, b2v = lo ? pd2 : d2;
    const int   A0 = lo ? i0 : pi0, A1 = lo ? i1 : pi1, A2 = lo ? i2 : pi2;
    const int   B0 = lo ? pi0 : i0, B1 = lo ? pi1 : i1, B2 = lo ? pi2 : i2;
    const bool c0 = b0 < a0;             // strict: a wins ties (lower indices)
    const bool cb1a0 = b1v < a0, cb0a1 = b0 < a1;
    const bool cb1a1 = b1v < a1, cb2a0 = b2v < a0, cb0a2 = b0 < a2;
    const float m0 = c0 ? b0 : a0;                 const int M0 = c0 ? B0 : A0;
    const float t1a = cb1a0 ? b1v : a0;            const int T1a = cb1a0 ? B1 : A0;
    const float t1b = cb0a1 ? b0 : a1;             const int T1b = cb0a1 ? B0 : A1;
    const float m1 = c0 ? t1a : t1b;               const int M1 = c0 ? T1a : T1b;
    const float sA = cb2a0 ? b2v : a0;             const int SA = cb2a0 ? B2 : A0;
    const float sB = cb1a1 ? b1v : a1;             const int SB = cb1a1 ? B1 : A1;
    const float sD = cb0a2 ? b0 : a2;              const int SD = cb0a2 ? B0 : A2;
    const float m2 = c0 ? (cb1a0 ? sA : sB) : (cb0a1 ? sB : sD);
    const int   M2 = c0 ? (cb1a0 ? SA : SB) : (cb0a1 ? SB : SD);
    d0 = m0; d1 = m1; d2 = m2; i0 = M0; i1 = M1; i2 = M2;
  }

  // ---- interpolation weights (redundant on all 8 lanes of the q-group) ----
  float w0f, w1f, w2f;
  {
    const float t0 = sqrtf(fmaxf(d0, 0.f)), t1 = sqrtf(fmaxf(d1, 0.f)),
                t2 = sqrtf(fmaxf(d2, 0.f));
    const float r0 = 1.0f / (t0 + 1e-8f), r1 = 1.0f / (t1 + 1e-8f),
                r2 = 1.0f / (t2 + 1e-8f);
    const float rs = __fadd_rn(__fadd_rn(r0, r1), r2);
    w0f = r0 / rs; w1f = r1 / rs; w2f = r2 / rs;
  }

  // ---- build rows 0..255: software-pipelined row-coalesced gather ----
  {
    const float* fb = featsT + (size_t)b * M_PTS * C0;
    float cw0 = rdlane_f(w0f, 0), cw1 = rdlane_f(w1f, 0), cw2 = rdlane_f(w2f, 0);
    float4 cf0 = *(const float4*)(fb + (size_t)__builtin_amdgcn_readlane(i0, 0) * C0 + l * 4);
    float4 cf1 = *(const float4*)(fb + (size_t)__builtin_amdgcn_readlane(i1, 0) * C0 + l * 4);
    float4 cf2 = *(const float4*)(fb + (size_t)__builtin_amdgcn_readlane(i2, 0) * C0 + l * 4);
#pragma unroll
    for (int qi = 0; qi < 8; ++qi) {
      float nw0, nw1, nw2; float4 nf0, nf1, nf2;
      if (qi < 7) {                      // issue next tile's loads early
        const int src = (qi + 1) * 8;
        nw0 = rdlane_f(w0f, src); nw1 = rdlane_f(w1f, src); nw2 = rdlane_f(w2f, src);
        nf0 = *(const float4*)(fb + (size_t)__builtin_amdgcn_readlane(i0, src) * C0 + l * 4);
        nf1 = *(const float4*)(fb + (size_t)__builtin_amdgcn_readlane(i1, src) * C0 + l * 4);
        nf2 = *(const float4*)(fb + (size_t)__builtin_amdgcn_readlane(i2, src) * C0 + l * 4);
      }
      ushort4 hv;
      hv.x = bf16c(cw0 * cf0.x + cw1 * cf1.x + cw2 * cf2.x);
      hv.y = bf16c(cw0 * cf0.y + cw1 * cf1.y + cw2 * cf2.y);
      hv.z = bf16c(cw0 * cf0.z + cw1 * cf1.z + cw2 * cf2.z);
      hv.w = bf16c(cw0 * cf0.w + cw1 * cf1.w + cw2 * cf2.w);
      const int nq = wv * 8 + qi;
      const int kq = l >> 1;
      const int u = kq * 32 + (nq ^ (kq & 7));
      *reinterpret_cast<ushort4*>(&pfB[u * 8 + (l & 1) * 4]) = hv;
      if (qi < 7) { cf0 = nf0; cf1 = nf1; cf2 = nf2; cw0 = nw0; cw1 = nw1; cw2 = nw2; }
    }
  }
  // ---- rows 256..383: skip feats from prefetch registers ----
#pragma unroll
  for (int it = 0; it < 8; ++it) {
    const int id = t + it * 256;
    const int r2 = id >> 5, nn = id & 31;
    const int k = C0 + 2 * r2;
    const int kq = k >> 3;
    const int u = kq * 32 + (nn ^ (kq & 7));
    ushort2 sv; sv.x = bf16c(skp[2 * it]); sv.y = bf16c(skp[2 * it + 1]);
    *reinterpret_cast<ushort2*>(&pfB[u * 8 + (k & 7)]) = sv;
  }
  __syncthreads();   // barrier 2: pfB complete

  const int c = l & 15, g = l >> 4;

  f32x4 acc[4][2];
#pragma unroll
  for (int i = 0; i < 4; ++i)
#pragma unroll
    for (int j = 0; j < 2; ++j) acc[i][j] = (f32x4){0.f, 0.f, 0.f, 0.f};

  // ---------------- GEMM1: h = relu(W1 @ pf + b1), K = 384 ----------------
  for (int kb = 0; kb < 12; ++kb) {
    const int kqg = kb * 4 + g;
    bf16x8 bfr[2], afr[4];
#pragma unroll
    for (int j = 0; j < 2; ++j)
      bfr[j] = *reinterpret_cast<const bf16x8*>(&pfB[(kqg * 32 + ((j * 16 + c) ^ (kqg & 7))) * 8]);
#pragma unroll
    for (int i = 0; i < 4; ++i)
      afr[i] = *reinterpret_cast<const bf16x8*>(&W1f[(((wv * 4 + i) * 12 + kb) * 4 + g) * 128 + c * 8]);
    __builtin_amdgcn_s_setprio(1);
#pragma unroll
    for (int i = 0; i < 4; ++i)
#pragma unroll
      for (int j = 0; j < 2; ++j)
        acc[i][j] = __builtin_amdgcn_mfma_f32_16x16x32_bf16(afr[i], bfr[j], acc[i][j], 0, 0, 0);
    __builtin_amdgcn_s_setprio(0);
  }

  // h -> hbuf (old pts region; pts dead after scan — no barrier needed)
#pragma unroll
  for (int i = 0; i < 4; ++i) {
    const int mbase = wv * 64 + i * 16 + g * 4;
    const float4 bias = *(const float4*)(b1 + mbase);
#pragma unroll
    for (int j = 0; j < 2; ++j) {
      const int nn = j * 16 + c;
      const int kq = mbase >> 3;
      const int u = kq * 32 + (nn ^ (kq & 7));
      ushort4 hv;
      hv.x = bf16c(fmaxf(acc[i][j].x + bias.x, 0.f));
      hv.y = bf16c(fmaxf(acc[i][j].y + bias.y, 0.f));
      hv.z = bf16c(fmaxf(acc[i][j].z + bias.z, 0.f));
      hv.w = bf16c(fmaxf(acc[i][j].w + bias.w, 0.f));
      *reinterpret_cast<ushort4*>(&hbuf[u * 8 + (mbase & 7)]) = hv;
    }
  }
  __syncthreads();   // barrier 3: h complete

#pragma unroll
  for (int i = 0; i < 4; ++i)
#pragma unroll
    for (int j = 0; j < 2; ++j) acc[i][j] = (f32x4){0.f, 0.f, 0.f, 0.f};

  // ---------------- GEMM2: out = relu(W2 @ h + b2), K = 256 ----------------
  for (int kb = 0; kb < 8; ++kb) {
    const int kqg = kb * 4 + g;
    bf16x8 bfr[2], afr[4];
#pragma unroll
    for (int j = 0; j < 2; ++j)
      bfr[j] = *reinterpret_cast<const bf16x8*>(&hbuf[(kqg * 32 + ((j * 16 + c) ^ (kqg & 7))) * 8]);
#pragma unroll
    for (int i = 0; i < 4; ++i)
      afr[i] = *reinterpret_cast<const bf16x8*>(&W2f[(((wv * 4 + i) * 8 + kb) * 4 + g) * 128 + c * 8]);
    __builtin_amdgcn_s_setprio(1);
#pragma unroll
    for (int i = 0; i < 4; ++i)
#pragma unroll
      for (int j = 0; j < 2; ++j)
        acc[i][j] = __builtin_amdgcn_mfma_f32_16x16x32_bf16(afr[i], bfr[j], acc[i][j], 0, 0, 0);
    __builtin_amdgcn_s_setprio(0);
  }

  // epilogue: relu(acc + b2) -> out
#pragma unroll
  for (int i = 0; i < 4; ++i) {
    const int mbase = wv * 64 + i * 16 + g * 4;
    const float4 bias = *(const float4*)(b2 + mbase);
#pragma unroll
    for (int j = 0; j < 2; ++j) {
      const int nn = n0 + j * 16 + c;
      out[((size_t)b * C2 + mbase + 0) * N_PTS + nn] = fmaxf(acc[i][j].x + bias.x, 0.f);
      out[((size_t)b * C2 + mbase + 1) * N_PTS + nn] = fmaxf(acc[i][j].y + bias.y, 0.f);
      out[((size_t)b * C2 + mbase + 2) * N_PTS + nn] = fmaxf(acc[i][j].z + bias.z, 0.f);
      out[((size_t)b * C2 + mbase + 3) * N_PTS + nn] = fmaxf(acc[i][j].w + bias.w, 0.f);
    }
  }
}

// ---------------------------------------------------------------------------
extern "C" void kernel_launch(void* const* d_in, const int* in_sizes, int n_in,
                              void* d_out, int out_size, void* d_ws, size_t ws_size,
                              hipStream_t stream) {
  const float* xyz   = (const float*)d_in[0];
  const float* pxyz  = (const float*)d_in[1];
  const float* feats = (const float*)d_in[2];
  const float* skip  = (const float*)d_in[3];
  const float* W1    = (const float*)d_in[4];
  const float* b1    = (const float*)d_in[5];
  const float* W2    = (const float*)d_in[6];
  const float* b2    = (const float*)d_in[7];
  float* out = (float*)d_out;

  float*  ws     = (float*)d_ws;
  float*  featsT = ws;                                           // 8*1024*256 f32
  ushort* W1f    = (ushort*)(featsT + (size_t)BS * M_PTS * C0);  // 98304 ushort
  ushort* W2f    = W1f + (size_t)C2 * K1DIM;                     // 65536 ushort

  prep_k<<<2432, 256, 0, stream>>>(feats, W1, W2, featsT, W1f, W2f);
  fp_fused_k<<<BS * (N_PTS / 32), 256, 0, stream>>>(xyz, pxyz, featsT, skip,
                                                    W1f, b1, W2f, b2, out);
}

// Round 15
// 45.304 us; speedup vs baseline: 1.2880x; 1.0203x over previous
//
#include <hip/hip_runtime.h>
#include <hip/hip_bf16.h>
#include <cstddef>
#include <cstdint>

#define BS    8
#define M_PTS 1024
#define N_PTS 4096
#define C0    256
#define C1    128
#define C2    256
#define K1DIM 384   // C0 + C1

typedef __attribute__((ext_vector_type(8))) short bf16x8;
typedef __attribute__((ext_vector_type(4))) float f32x4;

__device__ __forceinline__ ushort f2bf(float f) {
  union { float f; unsigned u; } v; v.f = f;
  unsigned r = v.u + 0x7fffu + ((v.u >> 16) & 1u);   // RNE
  return (ushort)(r >> 16);
}
// compiler-friendly bf16 convert (RNE; enables auto v_cvt_pk_bf16_f32 pairing)
__device__ __forceinline__ ushort bf16c(float f) {
  return __builtin_bit_cast(ushort, __float2bfloat16(f));
}

__device__ __forceinline__ float rdlane_f(float v, int lane) {
  union { float f; int i; } u; u.f = v;
  u.i = __builtin_amdgcn_readlane(u.i, lane);
  return u.f;
}

// ---------------------------------------------------------------------------
// Merged prep: blocks [0,2048) transpose feats (BS,C0,M)->(BS,M,C0);
// blocks [2048,2432) convert W1/W2 to bf16 MFMA A-fragment order
// ---------------------------------------------------------------------------
__global__ __launch_bounds__(256) void prep_k(
    const float* __restrict__ feats, const float* __restrict__ W1,
    const float* __restrict__ W2, float* __restrict__ featsT,
    ushort* __restrict__ W1f, ushort* __restrict__ W2f) {
  __shared__ float tile[32][33];
  const int t = threadIdx.x;
  if (blockIdx.x < 2048) {
    const int bx = blockIdx.x & 31;          // M tile
    const int by = (blockIdx.x >> 5) & 7;    // C0 tile
    const int bz = blockIdx.x >> 8;          // batch
    const int tx = t & 31, ty = t >> 5;
    const float* ip = feats + (size_t)bz * C0 * M_PTS;
    float*       op = featsT + (size_t)bz * C0 * M_PTS;
    const int r0 = by * 32, c0 = bx * 32;
#pragma unroll
    for (int i = 0; i < 4; ++i)
      tile[ty + i * 8][tx] = ip[(size_t)(r0 + ty + i * 8) * M_PTS + c0 + tx];
    __syncthreads();
#pragma unroll
    for (int i = 0; i < 4; ++i)
      op[(size_t)(c0 + ty + i * 8) * C0 + r0 + tx] = tile[tx][ty + i * 8];
  } else {
    const int id = (blockIdx.x - 2048) * 256 + t;
    if (id < C2 * K1DIM) {
      int m = id / K1DIM, k = id - m * K1DIM;
      int off = (((m >> 4) * 12 + (k >> 5)) * 4 + ((k >> 3) & 3)) * 128 + (m & 15) * 8 + (k & 7);
      W1f[off] = f2bf(W1[id]);
    }
    if (id < C2 * C2) {
      int m = id >> 8, k = id & 255;
      int off = (((m >> 4) * 8 + (k >> 5)) * 4 + ((k >> 3) & 3)) * 128 + (m & 15) * 8 + (k & 7);
      W2f[off] = f2bf(W2[id]);
    }
  }
}

// ---------------------------------------------------------------------------
// Fully fused per 32-query tile, 256 threads / 4 waves, LDS exactly 40960 B.
// r13 structure + (a) doubled-coord staging (d bit-identical: power-of-2
// scaling commutes with RN rounding), (b) software-prefetched W-fragments
// in both GEMM K-loops (hides L2 latency under MFMA).
// ---------------------------------------------------------------------------
__global__ __launch_bounds__(256, 4) void fp_fused_k(
    const float* __restrict__ xyz,      // (BS, M, 3)
    const float* __restrict__ pxyz,     // (BS, N, 3)
    const float* __restrict__ featsT,   // (BS, M, C0) f32
    const float* __restrict__ skip,     // (BS, C1, N) f32
    const ushort* __restrict__ W1f,
    const float* __restrict__ b1,
    const ushort* __restrict__ W2f,
    const float* __restrict__ b2,
    float* __restrict__ out) {          // (BS, C2, N) f32
  __shared__ float4 smemq[2560];                  // 40960 B total
  float4* pts4 = smemq;                           // [0,16384): 512 pairs x 32 B
  ushort* pfB  = (ushort*)(smemq + 1024);         // [16384,40960): 384x32 bf16
  ushort* hbuf = (ushort*)smemq;                  // [0,16384): 256x32 bf16 (aliases pts4)

  const int t  = threadIdx.x;
  const int b  = blockIdx.x & 7;                  // XCD-pinned batch
  const int n0 = (blockIdx.x >> 3) * 32;
  const int wv = t >> 6, l = t & 63;
  const int q  = t >> 3, sub = t & 7;

  // query coords (issued early, used in scan)
  const float qx = pxyz[((size_t)b * N_PTS + n0 + q) * 3 + 0];
  const float qy = pxyz[((size_t)b * N_PTS + n0 + q) * 3 + 1];
  const float qz = pxyz[((size_t)b * N_PTS + n0 + q) * 3 + 2];

  // ---- stage 2 SoA-pairs per thread, DOUBLED coords (s2 unscaled);
  //      slot U = p ^ ((p>>6)&7) ----
#pragma unroll
  for (int it = 0; it < 2; ++it) {
    const int p = t + it * 256;                   // pair index 0..511
    const float2* xb = (const float2*)(xyz + (size_t)b * 3 * M_PTS + 6 * p);
    const float2 A = xb[0], B = xb[1], C = xb[2];
    const float x0 = A.x, y0 = A.y, z0 = B.x, x1 = B.y, y1 = C.x, z1 = C.y;
    const float s0 = __fadd_rn(__fadd_rn(__fmul_rn(x0, x0), __fmul_rn(y0, y0)),
                               __fmul_rn(z0, z0));
    const float s1 = __fadd_rn(__fadd_rn(__fmul_rn(x1, x1), __fmul_rn(y1, y1)),
                               __fmul_rn(z1, z1));
    const int U = p ^ ((p >> 6) & 7);
    pts4[U * 2 + 0] = (float4){x0 + x0, x1 + x1, y0 + y0, y1 + y1};
    pts4[U * 2 + 1] = (float4){z0 + z0, z1 + z1, s0, s1};
  }

  // ---- skip prefetch into registers (HBM latency hides under the scan) ----
  float skp[16];
#pragma unroll
  for (int it = 0; it < 8; ++it) {
    const int id = t + it * 256;
    const int r2 = id >> 5, nn = id & 31;
    skp[2 * it + 0] = skip[((size_t)b * C1 + 2 * r2 + 0) * N_PTS + n0 + nn];
    skp[2 * it + 1] = skip[((size_t)b * C1 + 2 * r2 + 1) * N_PTS + n0 + nn];
  }

  const float qq = __fadd_rn(__fadd_rn(__fmul_rn(qx, qx), __fmul_rn(qy, qy)),
                             __fmul_rn(qz, qz));
  __syncthreads();   // barrier 1: pts staged

  // ---- scan: 8 subs x 64 pairs; d = (qq - dot2) + s2 (bit-exact) ----
  float d0 = 3.4e38f, d1 = 3.4e38f, d2 = 3.4e38f;
  int   i0 = 0, i1 = 0, i2 = 0;
  {
    int pe[8];
#pragma unroll
    for (int e = 0; e < 8; ++e) pe[e] = (sub * 64 + (e ^ sub)) * 2;  // de-swizzle
    for (int jb = 0; jb < 8; ++jb) {
#pragma unroll
      for (int e = 0; e < 8; ++e) {
        const float4 A  = pts4[pe[e] + jb * 16];     // {2x0,2x1,2y0,2y1}
        const float4 Bv = pts4[pe[e] + jb * 16 + 1]; // {2z0,2z1,s0,s1}
        {
          const float dot2 = __fadd_rn(__fadd_rn(__fmul_rn(qx, A.x), __fmul_rn(qy, A.z)),
                                       __fmul_rn(qz, Bv.x));
          const float d = __fadd_rn(__fsub_rn(qq, dot2), Bv.z);
          const int m = jb * 16 + 2 * e;
          const bool c0 = d < d0, c1 = d < d1, c2 = d < d2;
          i2 = c1 ? i1 : (c2 ? m : i2);
          i1 = c0 ? i0 : (c1 ? m : i1);
          i0 = c0 ? m : i0;
          d2 = __builtin_amdgcn_fmed3f(d, d1, d2);
          d1 = __builtin_amdgcn_fmed3f(d, d0, d1);
          d0 = fminf(d, d0);
        }
        {
          const float dot2 = __fadd_rn(__fadd_rn(__fmul_rn(qx, A.y), __fmul_rn(qy, A.w)),
                                       __fmul_rn(qz, Bv.y));
          const float d = __fadd_rn(__fsub_rn(qq, dot2), Bv.w);
          const int m = jb * 16 + 2 * e + 1;
          const bool c0 = d < d0, c1 = d < d1, c2 = d < d2;
          i2 = c1 ? i1 : (c2 ? m : i2);
          i1 = c0 ? i0 : (c1 ? m : i1);
          i0 = c0 ? m : i0;
          d2 = __builtin_amdgcn_fmed3f(d, d1, d2);
          d1 = __builtin_amdgcn_fmed3f(d, d0, d1);
          d0 = fminf(d, d0);
        }
      }
    }
    i0 += sub * 128; i1 += sub * 128; i2 += sub * 128;   // local -> global idx
  }

  // ---- in-register butterfly merge across subs (stable: lower sub wins ties)
#pragma unroll
  for (int mk = 1; mk <= 4; mk <<= 1) {
    const float pd0 = __shfl_xor(d0, mk), pd1 = __shfl_xor(d1, mk), pd2 = __shfl_xor(d2, mk);
    const int   pi0 = __shfl_xor(i0, mk), pi1 = __shfl_xor(i1, mk), pi2 = __shfl_xor(i2, mk);
    const bool lo = (sub & mk) == 0;
    const float a0 = lo ? d0 : pd0, a1 = lo ? d1 : pd1, a2 = lo ? d2 : pd2;
    const float b0 = lo ? pd0 : d0, b1v = lo ? pd1 : d1, b2v = lo ? pd2 : d2;
    const int   A0 = lo ? i0 : pi0, A1 = lo ? i1 : pi1, A2 = lo ? i2 : pi2;
    const int   B0 = lo ? pi0 : i0, B1 = lo ? pi1 : i1, B2 = lo ? pi2 : i2;
    const bool c0 = b0 < a0;             // strict: a wins ties (lower indices)
    const bool cb1a0 = b1v < a0, cb0a1 = b0 < a1;
    const bool cb1a1 = b1v < a1, cb2a0 = b2v < a0, cb0a2 = b0 < a2;
    const float m0 = c0 ? b0 : a0;                 const int M0 = c0 ? B0 : A0;
    const float t1a = cb1a0 ? b1v : a0;            const int T1a = cb1a0 ? B1 : A0;
    const float t1b = cb0a1 ? b0 : a1;             const int T1b = cb0a1 ? B0 : A1;
    const float m1 = c0 ? t1a : t1b;               const int M1 = c0 ? T1a : T1b;
    const float sA = cb2a0 ? b2v : a0;             const int SA = cb2a0 ? B2 : A0;
    const float sB = cb1a1 ? b1v : a1;             const int SB = cb1a1 ? B1 : A1;
    const float sD = cb0a2 ? b0 : a2;              const int SD = cb0a2 ? B0 : A2;
    const float m2 = c0 ? (cb1a0 ? sA : sB) : (cb0a1 ? sB : sD);
    const int   M2 = c0 ? (cb1a0 ? SA : SB) : (cb0a1 ? SB : SD);
    d0 = m0; d1 = m1; d2 = m2; i0 = M0; i1 = M1; i2 = M2;
  }

  // ---- interpolation weights (redundant on all 8 lanes of the q-group) ----
  float w0f, w1f, w2f;
  {
    const float t0 = sqrtf(fmaxf(d0, 0.f)), t1 = sqrtf(fmaxf(d1, 0.f)),
                t2 = sqrtf(fmaxf(d2, 0.f));
    const float r0 = 1.0f / (t0 + 1e-8f), r1 = 1.0f / (t1 + 1e-8f),
                r2 = 1.0f / (t2 + 1e-8f);
    const float rs = __fadd_rn(__fadd_rn(r0, r1), r2);
    w0f = r0 / rs; w1f = r1 / rs; w2f = r2 / rs;
  }

  // ---- build rows 0..255: software-pipelined row-coalesced gather ----
  {
    const float* fb = featsT + (size_t)b * M_PTS * C0;
    float cw0 = rdlane_f(w0f, 0), cw1 = rdlane_f(w1f, 0), cw2 = rdlane_f(w2f, 0);
    float4 cf0 = *(const float4*)(fb + (size_t)__builtin_amdgcn_readlane(i0, 0) * C0 + l * 4);
    float4 cf1 = *(const float4*)(fb + (size_t)__builtin_amdgcn_readlane(i1, 0) * C0 + l * 4);
    float4 cf2 = *(const float4*)(fb + (size_t)__builtin_amdgcn_readlane(i2, 0) * C0 + l * 4);
#pragma unroll
    for (int qi = 0; qi < 8; ++qi) {
      float nw0, nw1, nw2; float4 nf0, nf1, nf2;
      if (qi < 7) {                      // issue next tile's loads early
        const int src = (qi + 1) * 8;
        nw0 = rdlane_f(w0f, src); nw1 = rdlane_f(w1f, src); nw2 = rdlane_f(w2f, src);
        nf0 = *(const float4*)(fb + (size_t)__builtin_amdgcn_readlane(i0, src) * C0 + l * 4);
        nf1 = *(const float4*)(fb + (size_t)__builtin_amdgcn_readlane(i1, src) * C0 + l * 4);
        nf2 = *(const float4*)(fb + (size_t)__builtin_amdgcn_readlane(i2, src) * C0 + l * 4);
      }
      ushort4 hv;
      hv.x = bf16c(cw0 * cf0.x + cw1 * cf1.x + cw2 * cf2.x);
      hv.y = bf16c(cw0 * cf0.y + cw1 * cf1.y + cw2 * cf2.y);
      hv.z = bf16c(cw0 * cf0.z + cw1 * cf1.z + cw2 * cf2.z);
      hv.w = bf16c(cw0 * cf0.w + cw1 * cf1.w + cw2 * cf2.w);
      const int nq = wv * 8 + qi;
      const int kq = l >> 1;
      const int u = kq * 32 + (nq ^ (kq & 7));
      *reinterpret_cast<ushort4*>(&pfB[u * 8 + (l & 1) * 4]) = hv;
      if (qi < 7) { cf0 = nf0; cf1 = nf1; cf2 = nf2; cw0 = nw0; cw1 = nw1; cw2 = nw2; }
    }
  }
  // ---- rows 256..383: skip feats from prefetch registers ----
#pragma unroll
  for (int it = 0; it < 8; ++it) {
    const int id = t + it * 256;
    const int r2 = id >> 5, nn = id & 31;
    const int k = C0 + 2 * r2;
    const int kq = k >> 3;
    const int u = kq * 32 + (nn ^ (kq & 7));
    ushort2 sv; sv.x = bf16c(skp[2 * it]); sv.y = bf16c(skp[2 * it + 1]);
    *reinterpret_cast<ushort2*>(&pfB[u * 8 + (k & 7)]) = sv;
  }
  __syncthreads();   // barrier 2: pfB complete

  const int c = l & 15, g = l >> 4;

  f32x4 acc[4][2];
#pragma unroll
  for (int i = 0; i < 4; ++i)
#pragma unroll
    for (int j = 0; j < 2; ++j) acc[i][j] = (f32x4){0.f, 0.f, 0.f, 0.f};

  // ---------------- GEMM1: h = relu(W1 @ pf + b1), K = 384 ----------------
  {
    bf16x8 afr[4], nafr[4];
#pragma unroll
    for (int i = 0; i < 4; ++i)
      afr[i] = *reinterpret_cast<const bf16x8*>(&W1f[(((wv * 4 + i) * 12 + 0) * 4 + g) * 128 + c * 8]);
    for (int kb = 0; kb < 12; ++kb) {
      const int kqg = kb * 4 + g;
      bf16x8 bfr[2];
#pragma unroll
      for (int j = 0; j < 2; ++j)
        bfr[j] = *reinterpret_cast<const bf16x8*>(&pfB[(kqg * 32 + ((j * 16 + c) ^ (kqg & 7))) * 8]);
      if (kb < 11) {
#pragma unroll
        for (int i = 0; i < 4; ++i)
          nafr[i] = *reinterpret_cast<const bf16x8*>(&W1f[(((wv * 4 + i) * 12 + kb + 1) * 4 + g) * 128 + c * 8]);
      }
      __builtin_amdgcn_s_setprio(1);
#pragma unroll
      for (int i = 0; i < 4; ++i)
#pragma unroll
        for (int j = 0; j < 2; ++j)
          acc[i][j] = __builtin_amdgcn_mfma_f32_16x16x32_bf16(afr[i], bfr[j], acc[i][j], 0, 0, 0);
      __builtin_amdgcn_s_setprio(0);
      if (kb < 11) {
#pragma unroll
        for (int i = 0; i < 4; ++i) afr[i] = nafr[i];
      }
    }
  }

  // h -> hbuf (old pts region; pts dead after scan — no barrier needed)
#pragma unroll
  for (int i = 0; i < 4; ++i) {
    const int mbase = wv * 64 + i * 16 + g * 4;
    const float4 bias = *(const float4*)(b1 + mbase);
#pragma unroll
    for (int j = 0; j < 2; ++j) {
      const int nn = j * 16 + c;
      const int kq = mbase >> 3;
      const int u = kq * 32 + (nn ^ (kq & 7));
      ushort4 hv;
      hv.x = bf16c(fmaxf(acc[i][j].x + bias.x, 0.f));
      hv.y = bf16c(fmaxf(acc[i][j].y + bias.y, 0.f));
      hv.z = bf16c(fmaxf(acc[i][j].z + bias.z, 0.f));
      hv.w = bf16c(fmaxf(acc[i][j].w + bias.w, 0.f));
      *reinterpret_cast<ushort4*>(&hbuf[u * 8 + (mbase & 7)]) = hv;
    }
  }
  __syncthreads();   // barrier 3: h complete

#pragma unroll
  for (int i = 0; i < 4; ++i)
#pragma unroll
    for (int j = 0; j < 2; ++j) acc[i][j] = (f32x4){0.f, 0.f, 0.f, 0.f};

  // ---------------- GEMM2: out = relu(W2 @ h + b2), K = 256 ----------------
  {
    bf16x8 afr[4], nafr[4];
#pragma unroll
    for (int i = 0; i < 4; ++i)
      afr[i] = *reinterpret_cast<const bf16x8*>(&W2f[(((wv * 4 + i) * 8 + 0) * 4 + g) * 128 + c * 8]);
    for (int kb = 0; kb < 8; ++kb) {
      const int kqg = kb * 4 + g;
      bf16x8 bfr[2];
#pragma unroll
      for (int j = 0; j < 2; ++j)
        bfr[j] = *reinterpret_cast<const bf16x8*>(&hbuf[(kqg * 32 + ((j * 16 + c) ^ (kqg & 7))) * 8]);
      if (kb < 7) {
#pragma unroll
        for (int i = 0; i < 4; ++i)
          nafr[i] = *reinterpret_cast<const bf16x8*>(&W2f[(((wv * 4 + i) * 8 + kb + 1) * 4 + g) * 128 + c * 8]);
      }
      __builtin_amdgcn_s_setprio(1);
#pragma unroll
      for (int i = 0; i < 4; ++i)
#pragma unroll
        for (int j = 0; j < 2; ++j)
          acc[i][j] = __builtin_amdgcn_mfma_f32_16x16x32_bf16(afr[i], bfr[j], acc[i][j], 0, 0, 0);
      __builtin_amdgcn_s_setprio(0);
      if (kb < 7) {
#pragma unroll
        for (int i = 0; i < 4; ++i) afr[i] = nafr[i];
      }
    }
  }

  // epilogue: relu(acc + b2) -> out
#pragma unroll
  for (int i = 0; i < 4; ++i) {
    const int mbase = wv * 64 + i * 16 + g * 4;
    const float4 bias = *(const float4*)(b2 + mbase);
#pragma unroll
    for (int j = 0; j < 2; ++j) {
      const int nn = n0 + j * 16 + c;
      out[((size_t)b * C2 + mbase + 0) * N_PTS + nn] = fmaxf(acc[i][j].x + bias.x, 0.f);
      out[((size_t)b * C2 + mbase + 1) * N_PTS + nn] = fmaxf(acc[i][j].y + bias.y, 0.f);
      out[((size_t)b * C2 + mbase + 2) * N_PTS + nn] = fmaxf(acc[i][j].z + bias.z, 0.f);
      out[((size_t)b * C2 + mbase + 3) * N_PTS + nn] = fmaxf(acc[i][j].w + bias.w, 0.f);
    }
  }
}

// ---------------------------------------------------------------------------
extern "C" void kernel_launch(void* const* d_in, const int* in_sizes, int n_in,
                              void* d_out, int out_size, void* d_ws, size_t ws_size,
                              hipStream_t stream) {
  const float* xyz   = (const float*)d_in[0];
  const float* pxyz  = (const float*)d_in[1];
  const float* feats = (const float*)d_in[2];
  const float* skip  = (const float*)d_in[3];
  const float* W1    = (const float*)d_in[4];
  const float* b1    = (const float*)d_in[5];
  const float* W2    = (const float*)d_in[6];
  const float* b2    = (const float*)d_in[7];
  float* out = (float*)d_out;

  float*  ws     = (float*)d_ws;
  float*  featsT = ws;                                           // 8*1024*256 f32
  ushort* W1f    = (ushort*)(featsT + (size_t)BS * M_PTS * C0);  // 98304 ushort
  ushort* W2f    = W1f + (size_t)C2 * K1DIM;                     // 65536 ushort

  prep_k<<<2432, 256, 0, stream>>>(feats, W1, W2, featsT, W1f, W2f);
  fp_fused_k<<<BS * (N_PTS / 32), 256, 0, stream>>>(xyz, pxyz, featsT, skip,
                                                    W1f, b1, W2f, b2, out);
}